// Round 14
// baseline (1215.506 us; speedup 1.0000x reference)
//
#include <hip/hip_runtime.h>

#define SEQ   8192
#define VOCAB 128000
#define L     64
#define NCH   128   // SEQ / L

// ws layout (float offsets)
#define OFF_CMB    0        // CmbT[k][t] : [20][8192] fp32 combined, k-major
#define OFF_CVEC   163840   // cvecT[k][m][i] : [64][128][10]
#define OFF_AMAX   245760   // amax64[t] : 8192 x u64 packed (key<<32 | VOCAB-idx)
#define OFF_AMAX1  262144   // amax1[t] : 8192 x u32 sortable approx max
#define OFF_THRESH 270336   // thresh[t] fp32
#define OFF_CNORM  278528   // ||c_t||_2 fp32
#define OFF_WMAX   286720   // max_v ||W_v||_2 as u32 bits (+pad)
#define OFF_C32    286784   // c32[t][32] bf16 (131072 floats)
#define OFF_W32    417856   // W32[v][32] bf16 (2048000 floats)
// total 2,465,856 floats = 9.86 MB

typedef __attribute__((ext_vector_type(8))) short bf16x8;
typedef __attribute__((ext_vector_type(4))) float f32x4;

static __device__ inline unsigned short f2bf(float x) {
    unsigned u = __float_as_uint(x);
    u += 0x7FFF + ((u >> 16) & 1);          // RNE
    return (unsigned short)(u >> 16);
}
static __device__ inline unsigned sortable(float x) {
    unsigned u = __float_as_uint(x);
    return (u & 0x80000000u) ? ~u : (u | 0x80000000u);
}
static __device__ inline float unsortable(unsigned k) {
    unsigned u = (k & 0x80000000u) ? (k & 0x7FFFFFFFu) : ~k;
    return __uint_as_float(u);
}

// ---------------------------------------------------------------------------
// K1: gather embeddings -> CmbT rows 0..9; cvec; zero amax64/amax1/wmax.
// ---------------------------------------------------------------------------
__global__ void k_embed(const int* __restrict__ ix, const float* __restrict__ emb,
                        const float* __restrict__ Wih, const float* __restrict__ bih,
                        float* __restrict__ ws) {
    int t = blockIdx.x * blockDim.x + threadIdx.x;
    if (t >= SEQ) return;
    ((unsigned long long*)(ws + OFF_AMAX))[t] = 0ULL;
    ((unsigned*)(ws + OFF_AMAX1))[t] = 0u;
    if (t == 0) ((unsigned*)(ws + OFF_WMAX))[0] = 0u;

    int id = ix[t];
    float w[10];
    const float2* ep = (const float2*)(emb + (long long)id * 10);
#pragma unroll
    for (int j = 0; j < 5; j++) ((float2*)w)[j] = ep[j];
#pragma unroll
    for (int j = 0; j < 10; j++) ws[OFF_CMB + j * SEQ + t] = w[j];

    int m = t >> 6, k = t & 63;
    float* cv = ws + OFF_CVEC + (k * NCH + m) * 10;
#pragma unroll
    for (int i = 0; i < 10; i++) {
        float s = bih[i];
#pragma unroll
        for (int j = 0; j < 10; j++) s += Wih[i * 20 + j] * w[j];
        cv[i] = s;
    }
}

// ---------------------------------------------------------------------------
// K2: pack W -> bf16 [v][32] (pad 20->32 with zeros) + global max row-norm.
// ---------------------------------------------------------------------------
__global__ void k_pack_w(const float* __restrict__ Wio, float* __restrict__ ws) {
    int v = blockIdx.x * blockDim.x + threadIdx.x;
    if (v >= VOCAB) return;
    float w[20];
    const float4* r = (const float4*)(Wio + (long long)v * 20);
#pragma unroll
    for (int q = 0; q < 5; q++) ((float4*)w)[q] = r[q];
    float n2 = 0.f;
#pragma unroll
    for (int k = 0; k < 20; k++) n2 += w[k] * w[k];
    atomicMax((unsigned*)(ws + OFF_WMAX), __float_as_uint(sqrtf(n2)));

    unsigned short h[32];
#pragma unroll
    for (int k = 0; k < 20; k++) h[k] = f2bf(w[k]);
#pragma unroll
    for (int k = 20; k < 32; k++) h[k] = 0;
    uint4* dst = (uint4*)((unsigned short*)(ws + OFF_W32));
#pragma unroll
    for (int i = 0; i < 4; i++) {
        uint4 u;
        u.x = (unsigned)h[8*i+0] | ((unsigned)h[8*i+1] << 16);
        u.y = (unsigned)h[8*i+2] | ((unsigned)h[8*i+3] << 16);
        u.z = (unsigned)h[8*i+4] | ((unsigned)h[8*i+5] << 16);
        u.w = (unsigned)h[8*i+6] | ((unsigned)h[8*i+7] << 16);
        dst[v * 4 + i] = u;
    }
}

// ---------------------------------------------------------------------------
// K3: blocked scan of h_{t+1} = A h_t + c_t -> CmbT rows 10..19.
// ---------------------------------------------------------------------------
__global__ void k_scan(const float* __restrict__ Wih, float* __restrict__ ws) {
    __shared__ float P[100], Q[100];
    __shared__ float Dl[NCH][10];
    __shared__ float Hst[NCH][10];
    __shared__ float Hl[10];
    int tid = threadIdx.x;

    float Ar[10][10];
#pragma unroll
    for (int i = 0; i < 10; i++)
#pragma unroll
        for (int j = 0; j < 10; j++) Ar[i][j] = Wih[i * 20 + 10 + j];

    {   // phase A
        int m = tid;
        float h[10];
#pragma unroll
        for (int i = 0; i < 10; i++) h[i] = 0.f;
        const float* cvb = ws + OFF_CVEC;
        float2 buf[5];
        {
            const float2* cp = (const float2*)(cvb + m * 10);
#pragma unroll
            for (int j = 0; j < 5; j++) buf[j] = cp[j];
        }
        for (int k = 0; k < L; k++) {
            float cc[10];
#pragma unroll
            for (int j = 0; j < 5; j++) { cc[2*j] = buf[j].x; cc[2*j+1] = buf[j].y; }
            if (k + 1 < L) {
                const float2* cp = (const float2*)(cvb + ((k + 1) * NCH + m) * 10);
#pragma unroll
                for (int j = 0; j < 5; j++) buf[j] = cp[j];
            }
            float nh[10];
#pragma unroll
            for (int i = 0; i < 10; i++) {
                float s = cc[i];
#pragma unroll
                for (int j = 0; j < 10; j++) s += Ar[i][j] * h[j];
                nh[i] = s;
            }
#pragma unroll
            for (int i = 0; i < 10; i++) h[i] = nh[i];
        }
#pragma unroll
        for (int i = 0; i < 10; i++) Dl[m][i] = h[i];
    }

    if (tid < 100) P[tid] = Wih[(tid / 10) * 20 + 10 + (tid % 10)];
    __syncthreads();
    for (int it = 0; it < 6; it++) {
        if (tid < 100) {
            int i = tid / 10, j = tid % 10;
            float s = 0.f;
#pragma unroll
            for (int k = 0; k < 10; k++) s += P[i * 10 + k] * P[k * 10 + j];
            Q[tid] = s;
        }
        __syncthreads();
        if (tid < 100) P[tid] = Q[tid];
        __syncthreads();
    }

    if (tid < 10) Hl[tid] = 0.f;
    __syncthreads();
    if (tid < 10) {
        int i = tid;
        float a64[10];
#pragma unroll
        for (int j = 0; j < 10; j++) a64[j] = P[i * 10 + j];
        float hc = 0.f;
        for (int m = 0; m < NCH; m++) {
            Hst[m][i] = hc;
            float s = Dl[m][i];
#pragma unroll
            for (int j = 0; j < 10; j++) s += a64[j] * Hl[j];
            Hl[i] = s;
            hc = s;
        }
    }
    __syncthreads();

    {   // phase C
        int m = tid;
        float h[10];
#pragma unroll
        for (int i = 0; i < 10; i++) h[i] = Hst[m][i];
        const float* cvb = ws + OFF_CVEC;
        float2 buf[5];
        {
            const float2* cp = (const float2*)(cvb + m * 10);
#pragma unroll
            for (int j = 0; j < 5; j++) buf[j] = cp[j];
        }
        for (int k = 0; k < L; k++) {
            int tg = m * 64 + k;
            float cc[10];
#pragma unroll
            for (int j = 0; j < 5; j++) { cc[2*j] = buf[j].x; cc[2*j+1] = buf[j].y; }
            if (k + 1 < L) {
                const float2* cp = (const float2*)(cvb + ((k + 1) * NCH + m) * 10);
#pragma unroll
                for (int j = 0; j < 5; j++) buf[j] = cp[j];
            }
#pragma unroll
            for (int i = 0; i < 10; i++) ws[OFF_CMB + (10 + i) * SEQ + tg] = h[i];
            float nh[10];
#pragma unroll
            for (int i = 0; i < 10; i++) {
                float s = cc[i];
#pragma unroll
                for (int j = 0; j < 10; j++) s += Ar[i][j] * h[j];
                nh[i] = s;
            }
#pragma unroll
            for (int i = 0; i < 10; i++) h[i] = nh[i];
        }
    }
}

// ---------------------------------------------------------------------------
// K4: pack c -> bf16 [t][32] + ||c_t||_2.
// ---------------------------------------------------------------------------
__global__ void k_pack_c(float* __restrict__ ws) {
    int t = blockIdx.x * blockDim.x + threadIdx.x;
    if (t >= SEQ) return;
    float c[20];
#pragma unroll
    for (int k = 0; k < 20; k++) c[k] = ws[OFF_CMB + k * SEQ + t];
    float n2 = 0.f;
#pragma unroll
    for (int k = 0; k < 20; k++) n2 += c[k] * c[k];
    ws[OFF_CNORM + t] = sqrtf(n2);

    unsigned short h[32];
#pragma unroll
    for (int k = 0; k < 20; k++) h[k] = f2bf(c[k]);
#pragma unroll
    for (int k = 20; k < 32; k++) h[k] = 0;
    uint4* dst = (uint4*)((unsigned short*)(ws + OFF_C32));
#pragma unroll
    for (int i = 0; i < 4; i++) {
        uint4 u;
        u.x = (unsigned)h[8*i+0] | ((unsigned)h[8*i+1] << 16);
        u.y = (unsigned)h[8*i+2] | ((unsigned)h[8*i+3] << 16);
        u.z = (unsigned)h[8*i+4] | ((unsigned)h[8*i+5] << 16);
        u.w = (unsigned)h[8*i+6] | ((unsigned)h[8*i+7] << 16);
        dst[t * 4 + i] = u;
    }
}

// ---------------------------------------------------------------------------
// MFMA passes: grid 640 = 32 t-blocks (256 t) x 20 v-slices (6400 v = 25
// chunks of 256 rows; each chunk = 16 tiles of 16 v  -- R13 BUG: swept only
// 8 of 16, half the vocab unexamined; fixed to vt<16). Wave owns 64 t.
// A: c32[t0+lane&15][quad*8..+7] (m120-verified layout). B from LDS, 80 B
// row pitch. D: col=lane&15 = v, row = quad*4+reg = t (m89/m91-verified).
// Bias added exactly (fp32) via the accumulator init.
// ---------------------------------------------------------------------------
__global__ __launch_bounds__(256)
void k_max1(const float* __restrict__ ws, const float* __restrict__ bio,
            unsigned* __restrict__ amax1) {
    __shared__ unsigned short WlS[256 * 40];   // 20 KB (80 B pitch)
    __shared__ float Blf[256];

    int tid = threadIdx.x;
    int lane = tid & 63, wid = tid >> 6, quad = lane >> 4, col = lane & 15;
    int tb  = blockIdx.x / 20;               // t-block
    int sl  = blockIdx.x % 20;               // v-slice
    int t0w = tb * 256 + wid * 64;
    int v0s = sl * 6400;

    const unsigned short* c32 = (const unsigned short*)(ws + OFF_C32);
    const uint4* W32g = (const uint4*)((const unsigned short*)(ws + OFF_W32));

    bf16x8 a[4];
#pragma unroll
    for (int tt = 0; tt < 4; tt++)
        a[tt] = *(const bf16x8*)(c32 + (t0w + tt * 16 + col) * 32 + quad * 8);

    float run[4][4];
#pragma unroll
    for (int tt = 0; tt < 4; tt++)
#pragma unroll
        for (int g = 0; g < 4; g++) run[tt][g] = -3.4e38f;

    for (int ch = 0; ch < 25; ch++) {
        __syncthreads();
        int vb = v0s + ch * 256;
#pragma unroll
        for (int i = 0; i < 4; i++) {
            int idx = tid + 256 * i, row = idx >> 2, q = idx & 3;
            *((uint4*)&WlS[row * 40 + q * 8]) = W32g[(vb + row) * 4 + q];
        }
        if (tid < 64) ((float4*)Blf)[tid] = ((const float4*)(bio + vb))[tid];
        __syncthreads();

        for (int vt = 0; vt < 16; vt++) {           // FIXED: 16 tiles per chunk
            int r = vt * 16 + col;
            bf16x8 b = *(const bf16x8*)(&WlS[r * 40 + quad * 8]);
            float bias = Blf[r];
#pragma unroll
            for (int tt = 0; tt < 4; tt++) {
                f32x4 acc = {bias, bias, bias, bias};
                f32x4 d = __builtin_amdgcn_mfma_f32_16x16x32_bf16(a[tt], b, acc, 0, 0, 0);
#pragma unroll
                for (int g = 0; g < 4; g++) run[tt][g] = fmaxf(run[tt][g], d[g]);
            }
        }
    }

    // reduce over the 16 v-columns (lanes within quad), then atomic per t
#pragma unroll
    for (int tt = 0; tt < 4; tt++)
#pragma unroll
        for (int g = 0; g < 4; g++) {
            float r = run[tt][g];
            for (int off = 1; off < 16; off <<= 1)
                r = fmaxf(r, __shfl_xor(r, off));
            if (col == 0)
                atomicMax(&amax1[t0w + tt * 16 + quad * 4 + g], sortable(r));
        }
}

// ---------------------------------------------------------------------------
// K6: thresh[t] = maxap - margin. margin = 0.04*||c||*wmax = 2.56x the
// rigorous 2-eps bf16 bound (2 * 2^-8 * ||c|| * ||w||); any exact-argmax v
// provably satisfies d(v) >= thresh, and any non-candidate provably loses.
// ---------------------------------------------------------------------------
__global__ void k_thresh(float* __restrict__ ws) {
    int t = blockIdx.x * blockDim.x + threadIdx.x;
    if (t >= SEQ) return;
    float maxap = unsortable(((const unsigned*)(ws + OFF_AMAX1))[t]);
    float wmax  = __uint_as_float(((const unsigned*)(ws + OFF_WMAX))[0]);
    float marg  = 0.04f * ws[OFF_CNORM + t] * wmax + 1e-5f;
    ws[OFF_THRESH + t] = maxap - marg;
}

// ---------------------------------------------------------------------------
// K7: candidate pass — same MFMA sweep; lanes with D >= thresh do the exact
// fp32 dot and packed-u64 atomicMax (exact jnp.argmax, lowest idx on ties).
// ---------------------------------------------------------------------------
__global__ __launch_bounds__(256)
void k_cand(const float* __restrict__ ws, const float* __restrict__ Wio,
            const float* __restrict__ bio, unsigned long long* __restrict__ amax) {
    __shared__ unsigned short WlS[256 * 40];
    __shared__ float Blf[256];

    int tid = threadIdx.x;
    int lane = tid & 63, wid = tid >> 6, quad = lane >> 4, col = lane & 15;
    int tb  = blockIdx.x / 20;
    int sl  = blockIdx.x % 20;
    int t0w = tb * 256 + wid * 64;
    int v0s = sl * 6400;

    const unsigned short* c32 = (const unsigned short*)(ws + OFF_C32);
    const uint4* W32g = (const uint4*)((const unsigned short*)(ws + OFF_W32));
    const float* cmb = ws + OFF_CMB;

    bf16x8 a[4];
    float thr[4][4], thrmin[4];
#pragma unroll
    for (int tt = 0; tt < 4; tt++) {
        a[tt] = *(const bf16x8*)(c32 + (t0w + tt * 16 + col) * 32 + quad * 8);
        float mn = 3.4e38f;
#pragma unroll
        for (int g = 0; g < 4; g++) {
            thr[tt][g] = ws[OFF_THRESH + t0w + tt * 16 + quad * 4 + g];
            mn = fminf(mn, thr[tt][g]);
        }
        thrmin[tt] = mn;
    }

    for (int ch = 0; ch < 25; ch++) {
        __syncthreads();
        int vb = v0s + ch * 256;
#pragma unroll
        for (int i = 0; i < 4; i++) {
            int idx = tid + 256 * i, row = idx >> 2, q = idx & 3;
            *((uint4*)&WlS[row * 40 + q * 8]) = W32g[(vb + row) * 4 + q];
        }
        if (tid < 64) ((float4*)Blf)[tid] = ((const float4*)(bio + vb))[tid];
        __syncthreads();

        for (int vt = 0; vt < 16; vt++) {           // FIXED: 16 tiles per chunk
            int r = vt * 16 + col;
            bf16x8 b = *(const bf16x8*)(&WlS[r * 40 + quad * 8]);
            float bias = Blf[r];
            f32x4 d[4];
            int hit = 0;
#pragma unroll
            for (int tt = 0; tt < 4; tt++) {
                f32x4 acc = {bias, bias, bias, bias};
                d[tt] = __builtin_amdgcn_mfma_f32_16x16x32_bf16(a[tt], b, acc, 0, 0, 0);
                float hm = fmaxf(fmaxf(d[tt][0], d[tt][1]), fmaxf(d[tt][2], d[tt][3]));
                hit |= (hm >= thrmin[tt]) ? (1 << tt) : 0;
            }
            if (__any(hit)) {
                int v = vb + r;
#pragma unroll
                for (int tt = 0; tt < 4; tt++) {
#pragma unroll
                    for (int g = 0; g < 4; g++) {
                        if (d[tt][g] >= thr[tt][g]) {
                            int t = t0w + tt * 16 + quad * 4 + g;
                            const float* wr = Wio + (long long)v * 20;
                            float e = bio[v];
#pragma unroll
                            for (int k = 0; k < 20; k++)
                                e = fmaf(wr[k], cmb[k * SEQ + t], e);
                            unsigned key = sortable(e);
                            unsigned long long packed =
                                ((unsigned long long)key << 32) | (unsigned)(VOCAB - v);
                            atomicMax(&amax[t], packed);
                        }
                    }
                }
            }
        }
    }
}

// ---------------------------------------------------------------------------
// K8: unpack argmax -> float index
// ---------------------------------------------------------------------------
__global__ void k_out(const unsigned long long* __restrict__ amax,
                      float* __restrict__ out) {
    int t = blockIdx.x * blockDim.x + threadIdx.x;
    if (t >= SEQ) return;
    unsigned long long p = amax[t];
    int idx = VOCAB - (int)(p & 0xFFFFFFFFu);
    out[t] = (float)idx;
}

// ---------------------------------------------------------------------------
extern "C" void kernel_launch(void* const* d_in, const int* in_sizes, int n_in,
                              void* d_out, int out_size, void* d_ws, size_t ws_size,
                              hipStream_t stream) {
    (void)in_sizes; (void)n_in; (void)out_size; (void)ws_size;
    const int*   ix  = (const int*)d_in[0];
    const float* emb = (const float*)d_in[1];
    const float* Wih = (const float*)d_in[2];
    const float* bih = (const float*)d_in[3];
    const float* Wio = (const float*)d_in[4];
    const float* bio = (const float*)d_in[5];
    float* out = (float*)d_out;
    float* ws  = (float*)d_ws;
    unsigned long long* amax = (unsigned long long*)(ws + OFF_AMAX);
    unsigned* amax1 = (unsigned*)(ws + OFF_AMAX1);

    hipLaunchKernelGGL(k_embed,  dim3(SEQ / 256),   dim3(256), 0, stream, ix, emb, Wih, bih, ws);
    hipLaunchKernelGGL(k_pack_w, dim3(VOCAB / 256), dim3(256), 0, stream, Wio, ws);
    hipLaunchKernelGGL(k_scan,   dim3(1),           dim3(128), 0, stream, Wih, ws);
    hipLaunchKernelGGL(k_pack_c, dim3(SEQ / 256),   dim3(256), 0, stream, ws);
    hipLaunchKernelGGL(k_max1,   dim3(640),         dim3(256), 0, stream, ws, bio, amax1);
    hipLaunchKernelGGL(k_thresh, dim3(SEQ / 256),   dim3(256), 0, stream, ws);
    hipLaunchKernelGGL(k_cand,   dim3(640),         dim3(256), 0, stream, ws, Wio, bio, amax);
    hipLaunchKernelGGL(k_out,    dim3(SEQ / 256),   dim3(256), 0, stream, amax, out);
}

// Round 15
// 497.403 us; speedup vs baseline: 2.4437x; 2.4437x over previous
//
#include <hip/hip_runtime.h>

#define SEQ   8192
#define VOCAB 128000
#define L     64
#define NCH   128   // SEQ / L

// ws layout (float offsets)
#define OFF_CMB    0        // CmbT[k][t] : [20][8192] fp32 combined, k-major
#define OFF_CVEC   163840   // cvecT[k][m][i] : [64][128][10]
#define OFF_AMAX   245760   // amax64[t] : 8192 x u64 packed (key<<32 | VOCAB-idx)
#define OFF_AMAX1  262144   // amax1[t] : 8192 x u32 sortable approx max
#define OFF_THRESH 270336   // thresh[t] fp32
#define OFF_CNORM  278528   // ||c_t||_2 fp32
#define OFF_WMAX   286720   // max_v ||W_v||_2 as u32 bits (+pad)
#define OFF_C32    286784   // c32[t][32] bf16 (131072 floats)
#define OFF_W32    417856   // W32[v][32] bf16 (2048000 floats)
// total 2,465,856 floats = 9.86 MB

#define TBLK   16   // t-blocks of 512 t
#define VSLICE 50   // v-slices of 2560 v
#define CHUNKS 10   // 256-row chunks per slice
#define CCAP   2048 // candidate list capacity per block

typedef __attribute__((ext_vector_type(8))) short bf16x8;
typedef __attribute__((ext_vector_type(4))) float f32x4;

static __device__ inline unsigned short f2bf(float x) {
    unsigned u = __float_as_uint(x);
    u += 0x7FFF + ((u >> 16) & 1);          // RNE
    return (unsigned short)(u >> 16);
}
static __device__ inline unsigned sortable(float x) {
    unsigned u = __float_as_uint(x);
    return (u & 0x80000000u) ? ~u : (u | 0x80000000u);
}
static __device__ inline float unsortable(unsigned k) {
    unsigned u = (k & 0x80000000u) ? (k & 0x7FFFFFFFu) : ~k;
    return __uint_as_float(u);
}

// ---------------------------------------------------------------------------
// K1: gather embeddings -> CmbT rows 0..9; cvec; zero amax64/amax1/wmax.
// ---------------------------------------------------------------------------
__global__ void k_embed(const int* __restrict__ ix, const float* __restrict__ emb,
                        const float* __restrict__ Wih, const float* __restrict__ bih,
                        float* __restrict__ ws) {
    int t = blockIdx.x * blockDim.x + threadIdx.x;
    if (t >= SEQ) return;
    ((unsigned long long*)(ws + OFF_AMAX))[t] = 0ULL;
    ((unsigned*)(ws + OFF_AMAX1))[t] = 0u;
    if (t == 0) ((unsigned*)(ws + OFF_WMAX))[0] = 0u;

    int id = ix[t];
    float w[10];
    const float2* ep = (const float2*)(emb + (long long)id * 10);
#pragma unroll
    for (int j = 0; j < 5; j++) ((float2*)w)[j] = ep[j];
#pragma unroll
    for (int j = 0; j < 10; j++) ws[OFF_CMB + j * SEQ + t] = w[j];

    int m = t >> 6, k = t & 63;
    float* cv = ws + OFF_CVEC + (k * NCH + m) * 10;
#pragma unroll
    for (int i = 0; i < 10; i++) {
        float s = bih[i];
#pragma unroll
        for (int j = 0; j < 10; j++) s += Wih[i * 20 + j] * w[j];
        cv[i] = s;
    }
}

// ---------------------------------------------------------------------------
// K2: pack W -> bf16 [v][32] (pad 20->32 with zeros) + global max row-norm.
// ---------------------------------------------------------------------------
__global__ void k_pack_w(const float* __restrict__ Wio, float* __restrict__ ws) {
    int v = blockIdx.x * blockDim.x + threadIdx.x;
    if (v >= VOCAB) return;
    float w[20];
    const float4* r = (const float4*)(Wio + (long long)v * 20);
#pragma unroll
    for (int q = 0; q < 5; q++) ((float4*)w)[q] = r[q];
    float n2 = 0.f;
#pragma unroll
    for (int k = 0; k < 20; k++) n2 += w[k] * w[k];
    atomicMax((unsigned*)(ws + OFF_WMAX), __float_as_uint(sqrtf(n2)));

    unsigned short h[32];
#pragma unroll
    for (int k = 0; k < 20; k++) h[k] = f2bf(w[k]);
#pragma unroll
    for (int k = 20; k < 32; k++) h[k] = 0;
    uint4* dst = (uint4*)((unsigned short*)(ws + OFF_W32));
#pragma unroll
    for (int i = 0; i < 4; i++) {
        uint4 u;
        u.x = (unsigned)h[8*i+0] | ((unsigned)h[8*i+1] << 16);
        u.y = (unsigned)h[8*i+2] | ((unsigned)h[8*i+3] << 16);
        u.z = (unsigned)h[8*i+4] | ((unsigned)h[8*i+5] << 16);
        u.w = (unsigned)h[8*i+6] | ((unsigned)h[8*i+7] << 16);
        dst[v * 4 + i] = u;
    }
}

// ---------------------------------------------------------------------------
// K3: blocked scan of h_{t+1} = A h_t + c_t -> CmbT rows 10..19.
// ---------------------------------------------------------------------------
__global__ void k_scan(const float* __restrict__ Wih, float* __restrict__ ws) {
    __shared__ float P[100], Q[100];
    __shared__ float Dl[NCH][10];
    __shared__ float Hst[NCH][10];
    __shared__ float Hl[10];
    int tid = threadIdx.x;

    float Ar[10][10];
#pragma unroll
    for (int i = 0; i < 10; i++)
#pragma unroll
        for (int j = 0; j < 10; j++) Ar[i][j] = Wih[i * 20 + 10 + j];

    {   // phase A
        int m = tid;
        float h[10];
#pragma unroll
        for (int i = 0; i < 10; i++) h[i] = 0.f;
        const float* cvb = ws + OFF_CVEC;
        float2 buf[5];
        {
            const float2* cp = (const float2*)(cvb + m * 10);
#pragma unroll
            for (int j = 0; j < 5; j++) buf[j] = cp[j];
        }
        for (int k = 0; k < L; k++) {
            float cc[10];
#pragma unroll
            for (int j = 0; j < 5; j++) { cc[2*j] = buf[j].x; cc[2*j+1] = buf[j].y; }
            if (k + 1 < L) {
                const float2* cp = (const float2*)(cvb + ((k + 1) * NCH + m) * 10);
#pragma unroll
                for (int j = 0; j < 5; j++) buf[j] = cp[j];
            }
            float nh[10];
#pragma unroll
            for (int i = 0; i < 10; i++) {
                float s = cc[i];
#pragma unroll
                for (int j = 0; j < 10; j++) s += Ar[i][j] * h[j];
                nh[i] = s;
            }
#pragma unroll
            for (int i = 0; i < 10; i++) h[i] = nh[i];
        }
#pragma unroll
        for (int i = 0; i < 10; i++) Dl[m][i] = h[i];
    }

    if (tid < 100) P[tid] = Wih[(tid / 10) * 20 + 10 + (tid % 10)];
    __syncthreads();
    for (int it = 0; it < 6; it++) {
        if (tid < 100) {
            int i = tid / 10, j = tid % 10;
            float s = 0.f;
#pragma unroll
            for (int k = 0; k < 10; k++) s += P[i * 10 + k] * P[k * 10 + j];
            Q[tid] = s;
        }
        __syncthreads();
        if (tid < 100) P[tid] = Q[tid];
        __syncthreads();
    }

    if (tid < 10) Hl[tid] = 0.f;
    __syncthreads();
    if (tid < 10) {
        int i = tid;
        float a64[10];
#pragma unroll
        for (int j = 0; j < 10; j++) a64[j] = P[i * 10 + j];
        float hc = 0.f;
        for (int m = 0; m < NCH; m++) {
            Hst[m][i] = hc;
            float s = Dl[m][i];
#pragma unroll
            for (int j = 0; j < 10; j++) s += a64[j] * Hl[j];
            Hl[i] = s;
            hc = s;
        }
    }
    __syncthreads();

    {   // phase C
        int m = tid;
        float h[10];
#pragma unroll
        for (int i = 0; i < 10; i++) h[i] = Hst[m][i];
        const float* cvb = ws + OFF_CVEC;
        float2 buf[5];
        {
            const float2* cp = (const float2*)(cvb + m * 10);
#pragma unroll
            for (int j = 0; j < 5; j++) buf[j] = cp[j];
        }
        for (int k = 0; k < L; k++) {
            int tg = m * 64 + k;
            float cc[10];
#pragma unroll
            for (int j = 0; j < 5; j++) { cc[2*j] = buf[j].x; cc[2*j+1] = buf[j].y; }
            if (k + 1 < L) {
                const float2* cp = (const float2*)(cvb + ((k + 1) * NCH + m) * 10);
#pragma unroll
                for (int j = 0; j < 5; j++) buf[j] = cp[j];
            }
#pragma unroll
            for (int i = 0; i < 10; i++) ws[OFF_CMB + (10 + i) * SEQ + tg] = h[i];
            float nh[10];
#pragma unroll
            for (int i = 0; i < 10; i++) {
                float s = cc[i];
#pragma unroll
                for (int j = 0; j < 10; j++) s += Ar[i][j] * h[j];
                nh[i] = s;
            }
#pragma unroll
            for (int i = 0; i < 10; i++) h[i] = nh[i];
        }
    }
}

// ---------------------------------------------------------------------------
// K4: pack c -> bf16 [t][32] + ||c_t||_2.
// ---------------------------------------------------------------------------
__global__ void k_pack_c(float* __restrict__ ws) {
    int t = blockIdx.x * blockDim.x + threadIdx.x;
    if (t >= SEQ) return;
    float c[20];
#pragma unroll
    for (int k = 0; k < 20; k++) c[k] = ws[OFF_CMB + k * SEQ + t];
    float n2 = 0.f;
#pragma unroll
    for (int k = 0; k < 20; k++) n2 += c[k] * c[k];
    ws[OFF_CNORM + t] = sqrtf(n2);

    unsigned short h[32];
#pragma unroll
    for (int k = 0; k < 20; k++) h[k] = f2bf(c[k]);
#pragma unroll
    for (int k = 20; k < 32; k++) h[k] = 0;
    uint4* dst = (uint4*)((unsigned short*)(ws + OFF_C32));
#pragma unroll
    for (int i = 0; i < 4; i++) {
        uint4 u;
        u.x = (unsigned)h[8*i+0] | ((unsigned)h[8*i+1] << 16);
        u.y = (unsigned)h[8*i+2] | ((unsigned)h[8*i+3] << 16);
        u.z = (unsigned)h[8*i+4] | ((unsigned)h[8*i+5] << 16);
        u.w = (unsigned)h[8*i+6] | ((unsigned)h[8*i+7] << 16);
        dst[t * 4 + i] = u;
    }
}

// ---------------------------------------------------------------------------
// MFMA passes: grid 800 = 16 t-blocks (512 t) x 50 v-slices (2560 v = 10
// chunks of 256 rows, 16 tiles each). Wave owns 128 t = 8 acc tiles (8 MFMA
// per B-read). LDS W pitch = 64 B (NO pad): tile read is lane-contiguous
// 16 B/lane over 1024 B -> conflict-free (R14's 80 B pitch put all 16 cols
// on the same banks: 6.1M conflicts). Staging is a flat uint4 copy.
// A: c32[t0w+tt*16+col][quad*8..] ; D: t = t0w+tt*16+quad*4+g, v = vb+vt*16+col
// (R14-verified). Bias exact (fp32) via accumulator init.
// ---------------------------------------------------------------------------
__global__ __launch_bounds__(256)
void k_max1(const float* __restrict__ ws, const float* __restrict__ bio,
            unsigned* __restrict__ amax1) {
    __shared__ unsigned short WlS[256 * 32];   // 16 KB, 64 B pitch
    __shared__ float Blf[256];

    int tid = threadIdx.x;
    int lane = tid & 63, wid = tid >> 6, quad = lane >> 4, col = lane & 15;
    int tb  = blockIdx.x / VSLICE;
    int sl  = blockIdx.x % VSLICE;
    int t0w = tb * 512 + wid * 128;
    int v0s = sl * 2560;

    const unsigned short* c32 = (const unsigned short*)(ws + OFF_C32);
    const uint4* W32g = (const uint4*)((const unsigned short*)(ws + OFF_W32));

    bf16x8 a[8];
#pragma unroll
    for (int tt = 0; tt < 8; tt++)
        a[tt] = *(const bf16x8*)(c32 + (t0w + tt * 16 + col) * 32 + quad * 8);

    float run[8][4];
#pragma unroll
    for (int tt = 0; tt < 8; tt++)
#pragma unroll
        for (int g = 0; g < 4; g++) run[tt][g] = -3.4e38f;

    for (int ch = 0; ch < CHUNKS; ch++) {
        __syncthreads();
        int vb = v0s + ch * 256;
#pragma unroll
        for (int i = 0; i < 4; i++)
            ((uint4*)WlS)[tid + 256 * i] = W32g[vb * 4 + tid + 256 * i];
        if (tid < 64) ((float4*)Blf)[tid] = ((const float4*)(bio + vb))[tid];
        __syncthreads();

        for (int vt = 0; vt < 16; vt++) {
            bf16x8 b = *(const bf16x8*)(WlS + (vt * 16 + col) * 32 + quad * 8);
            float bias = Blf[vt * 16 + col];
#pragma unroll
            for (int tt = 0; tt < 8; tt++) {
                f32x4 acc = {bias, bias, bias, bias};
                f32x4 d = __builtin_amdgcn_mfma_f32_16x16x32_bf16(a[tt], b, acc, 0, 0, 0);
#pragma unroll
                for (int g = 0; g < 4; g++) run[tt][g] = fmaxf(run[tt][g], d[g]);
            }
        }
    }

    // reduce over the 16 v-columns (xor 1,2,4,8 within quad group)
#pragma unroll
    for (int tt = 0; tt < 8; tt++)
#pragma unroll
        for (int g = 0; g < 4; g++) {
            float r = run[tt][g];
            for (int off = 1; off < 16; off <<= 1)
                r = fmaxf(r, __shfl_xor(r, off));
            if (col == 0)
                atomicMax(&amax1[t0w + tt * 16 + quad * 4 + g], sortable(r));
        }
}

// ---------------------------------------------------------------------------
// K6: thresh[t] = maxap - margin. margin = 0.04*||c||*wmax = 2.56x the
// rigorous 2-eps bf16 bound -> exact argmax provably among candidates.
// ---------------------------------------------------------------------------
__global__ void k_thresh(float* __restrict__ ws) {
    int t = blockIdx.x * blockDim.x + threadIdx.x;
    if (t >= SEQ) return;
    float maxap = unsortable(((const unsigned*)(ws + OFF_AMAX1))[t]);
    float wmax  = __uint_as_float(((const unsigned*)(ws + OFF_WMAX))[0]);
    float marg  = 0.04f * ws[OFF_CNORM + t] * wmax + 1e-5f;
    ws[OFF_THRESH + t] = maxap - marg;
}

// ---------------------------------------------------------------------------
// K7: candidate pass. Hot loop only compares and appends (t<<17|v) to an LDS
// list (expected ~31 hits/block, cap 2048). Exact fp32 fixup runs in a block
// epilogue -> hot-loop live set ~95 VGPRs (R14's inline fixup forced 256 ->
// 1 wave/SIMD). Exact jnp.argmax semantics via packed-u64 atomicMax.
// ---------------------------------------------------------------------------
__global__ __launch_bounds__(256)
void k_cand(const float* __restrict__ ws, const float* __restrict__ Wio,
            const float* __restrict__ bio, unsigned long long* __restrict__ amax) {
    __shared__ unsigned short WlS[256 * 32];   // 16 KB
    __shared__ float Blf[256];
    __shared__ unsigned cand[CCAP];            // 8 KB
    __shared__ unsigned cnt;

    int tid = threadIdx.x;
    int lane = tid & 63, wid = tid >> 6, quad = lane >> 4, col = lane & 15;
    int tb  = blockIdx.x / VSLICE;
    int sl  = blockIdx.x % VSLICE;
    int t0w = tb * 512 + wid * 128;
    int v0s = sl * 2560;
    if (tid == 0) cnt = 0;

    const unsigned short* c32 = (const unsigned short*)(ws + OFF_C32);
    const uint4* W32g = (const uint4*)((const unsigned short*)(ws + OFF_W32));

    bf16x8 a[8];
    float thr[8][4], thrmin[8];
#pragma unroll
    for (int tt = 0; tt < 8; tt++) {
        a[tt] = *(const bf16x8*)(c32 + (t0w + tt * 16 + col) * 32 + quad * 8);
        float mn = 3.4e38f;
#pragma unroll
        for (int g = 0; g < 4; g++) {
            thr[tt][g] = ws[OFF_THRESH + t0w + tt * 16 + quad * 4 + g];
            mn = fminf(mn, thr[tt][g]);
        }
        thrmin[tt] = mn;
    }

    for (int ch = 0; ch < CHUNKS; ch++) {
        __syncthreads();
        int vb = v0s + ch * 256;
#pragma unroll
        for (int i = 0; i < 4; i++)
            ((uint4*)WlS)[tid + 256 * i] = W32g[vb * 4 + tid + 256 * i];
        if (tid < 64) ((float4*)Blf)[tid] = ((const float4*)(bio + vb))[tid];
        __syncthreads();

        for (int vt = 0; vt < 16; vt++) {
            bf16x8 b = *(const bf16x8*)(WlS + (vt * 16 + col) * 32 + quad * 8);
            float bias = Blf[vt * 16 + col];
            int v = vb + vt * 16 + col;
#pragma unroll
            for (int tt = 0; tt < 8; tt++) {
                f32x4 acc = {bias, bias, bias, bias};
                f32x4 d = __builtin_amdgcn_mfma_f32_16x16x32_bf16(a[tt], b, acc, 0, 0, 0);
                float hm = fmaxf(fmaxf(d[0], d[1]), fmaxf(d[2], d[3]));
                if (hm >= thrmin[tt]) {
#pragma unroll
                    for (int g = 0; g < 4; g++) {
                        if (d[g] >= thr[tt][g]) {
                            unsigned t = (unsigned)(t0w + tt * 16 + quad * 4 + g);
                            unsigned idx = atomicAdd(&cnt, 1u);
                            if (idx < CCAP) cand[idx] = (t << 17) | (unsigned)v;
                        }
                    }
                }
            }
        }
    }

    __syncthreads();
    // epilogue: exact fp32 re-evaluation of candidates
    unsigned n = cnt < CCAP ? cnt : CCAP;
    const float* cmb = ws + OFF_CMB;
    for (unsigned i = tid; i < n; i += 256) {
        unsigned e = cand[i];
        int t = (int)(e >> 17);
        int v = (int)(e & 0x1FFFFu);
        const float* wr = Wio + (long long)v * 20;
        float ex = bio[v];
#pragma unroll
        for (int k = 0; k < 20; k++)
            ex = fmaf(wr[k], cmb[k * SEQ + t], ex);
        unsigned key = sortable(ex);
        unsigned long long packed =
            ((unsigned long long)key << 32) | (unsigned)(VOCAB - v);
        atomicMax(&amax[t], packed);
    }
}

// ---------------------------------------------------------------------------
// K8: unpack argmax -> float index
// ---------------------------------------------------------------------------
__global__ void k_out(const unsigned long long* __restrict__ amax,
                      float* __restrict__ out) {
    int t = blockIdx.x * blockDim.x + threadIdx.x;
    if (t >= SEQ) return;
    unsigned long long p = amax[t];
    int idx = VOCAB - (int)(p & 0xFFFFFFFFu);
    out[t] = (float)idx;
}

// ---------------------------------------------------------------------------
extern "C" void kernel_launch(void* const* d_in, const int* in_sizes, int n_in,
                              void* d_out, int out_size, void* d_ws, size_t ws_size,
                              hipStream_t stream) {
    (void)in_sizes; (void)n_in; (void)out_size; (void)ws_size;
    const int*   ix  = (const int*)d_in[0];
    const float* emb = (const float*)d_in[1];
    const float* Wih = (const float*)d_in[2];
    const float* bih = (const float*)d_in[3];
    const float* Wio = (const float*)d_in[4];
    const float* bio = (const float*)d_in[5];
    float* out = (float*)d_out;
    float* ws  = (float*)d_ws;
    unsigned long long* amax = (unsigned long long*)(ws + OFF_AMAX);
    unsigned* amax1 = (unsigned*)(ws + OFF_AMAX1);

    hipLaunchKernelGGL(k_embed,  dim3(SEQ / 256),   dim3(256), 0, stream, ix, emb, Wih, bih, ws);
    hipLaunchKernelGGL(k_pack_w, dim3(VOCAB / 256), dim3(256), 0, stream, Wio, ws);
    hipLaunchKernelGGL(k_scan,   dim3(1),           dim3(128), 0, stream, Wih, ws);
    hipLaunchKernelGGL(k_pack_c, dim3(SEQ / 256),   dim3(256), 0, stream, ws);
    hipLaunchKernelGGL(k_max1,   dim3(TBLK * VSLICE), dim3(256), 0, stream, ws, bio, amax1);
    hipLaunchKernelGGL(k_thresh, dim3(SEQ / 256),   dim3(256), 0, stream, ws);
    hipLaunchKernelGGL(k_cand,   dim3(TBLK * VSLICE), dim3(256), 0, stream, ws, Wio, bio, amax);
    hipLaunchKernelGGL(k_out,    dim3(SEQ / 256),   dim3(256), 0, stream, amax, out);
}